// Round 1
// baseline (234.054 us; speedup 1.0000x reference)
//
#include <hip/hip_runtime.h>
#include <cstdint>
#include <cstddef>

// Problem constants (B=8, T=64, F=16, E=256, H=8)
constexpr int E = 256;
constexpr int H = 8;
constexpr int D = 32;        // head dim
constexpr int N = 1024;      // T*F positions per (b,h)
constexpr int R = 8192;      // B*N rows
constexpr int BH = 64;       // B*H
constexpr float SCALE = 0.17677669529663687f;  // 1/sqrt(32)

// ---------------- Kernel 1: QKV projections, head-split scatter ----------------
// C = X @ W + bias ; store to {Q,K,V}h[(b*H+h)*N + n][dd]   (n = t*F+f, c = h*32+dd)
__global__ __launch_bounds__(256) void proj_kernel(
    const float* __restrict__ q_in, const float* __restrict__ k_in, const float* __restrict__ v_in,
    const float* __restrict__ Wq, const float* __restrict__ bq,
    const float* __restrict__ Wk, const float* __restrict__ bk,
    const float* __restrict__ Wv, const float* __restrict__ bv,
    float* __restrict__ Qh, float* __restrict__ Kh, float* __restrict__ Vh)
{
    const int which = blockIdx.z;
    const float* X    = (which == 0) ? q_in : (which == 1) ? k_in : v_in;
    const float* W    = (which == 0) ? Wq   : (which == 1) ? Wk   : Wv;
    const float* bias = (which == 0) ? bq   : (which == 1) ? bk   : bv;
    float* Out        = (which == 0) ? Qh   : (which == 1) ? Kh   : Vh;

    __shared__ float At[16][68];   // A tile transposed: At[k][r]
    __shared__ float Bs[16][68];   // B tile: Bs[k][c]

    const int tid = threadIdx.x;
    const int tx = tid & 15, ty = tid >> 4;
    const int row0 = blockIdx.x * 64;
    const int col0 = blockIdx.y * 64;

    float acc[4][4] = {};

    for (int k0 = 0; k0 < E; k0 += 16) {
        __syncthreads();
        #pragma unroll
        for (int it = 0; it < 4; ++it) {
            int i = tid + it * 256;
            int k = i & 15, r = i >> 4;
            At[k][r] = X[(size_t)(row0 + r) * E + k0 + k];
        }
        #pragma unroll
        for (int it = 0; it < 4; ++it) {
            int i = tid + it * 256;
            int c = i & 63, k = i >> 6;
            Bs[k][c] = W[(size_t)(k0 + k) * E + col0 + c];
        }
        __syncthreads();
        #pragma unroll
        for (int kk = 0; kk < 16; ++kk) {
            float a[4], b[4];
            #pragma unroll
            for (int i = 0; i < 4; ++i) a[i] = At[kk][ty * 4 + i];
            #pragma unroll
            for (int j = 0; j < 4; ++j) b[j] = Bs[kk][tx * 4 + j];
            #pragma unroll
            for (int i = 0; i < 4; ++i)
                #pragma unroll
                for (int j = 0; j < 4; ++j)
                    acc[i][j] += a[i] * b[j];
        }
    }

    #pragma unroll
    for (int i = 0; i < 4; ++i) {
        int gr = row0 + ty * 4 + i;
        int b = gr >> 10, n = gr & (N - 1);
        #pragma unroll
        for (int j = 0; j < 4; ++j) {
            int gc = col0 + tx * 4 + j;
            int h = gc >> 5, dd = gc & 31;
            Out[((size_t)((b * H + h) * N + n)) * D + dd] = acc[i][j] + bias[gc];
        }
    }
}

// ---------------- Kernel 2: scores + softmax-denominator + s partials ----------
// Per block: one (b,h), 128 query columns (m-chunk). S[n,m] = K[n].Q[m]*SCALE.
// Pass 1: Z_m = sum_n exp(S[n,m])   (no max subtraction: |S| <~ 4, safe in fp32)
// Pass 2: s_part[n] = sum_{m in chunk} exp(S[n,m]) / Z_m
__global__ __launch_bounds__(256) void scores_kernel(
    const float* __restrict__ Qh, const float* __restrict__ Kh,
    float* __restrict__ spart)
{
    const int bh = blockIdx.x;   // 0..63
    const int mc = blockIdx.y;   // 0..7  (columns mc*128 .. +128)
    const int tid = threadIdx.x;
    const int tm = tid & 15;     // column group (8 cols each)
    const int tn = tid >> 4;     // row group (8 rows each)

    __shared__ float Kt[32][132];     // [d][n_local], rows 16B-aligned (132*4=528)
    __shared__ float Qt[32][132];     // [d][m_local]
    __shared__ float redz[16][128];
    __shared__ float cinv[128];
    __shared__ float s_local[1024];

    const float* Qb = Qh + (size_t)bh * (N * D);
    const float* Kb = Kh + (size_t)bh * (N * D);

    // Load Q chunk transposed + zero s_local
    #pragma unroll
    for (int it = 0; it < 16; ++it) {
        int i = tid + it * 256;
        int m = i >> 5, d = i & 31;
        Qt[d][m] = Qb[(size_t)(mc * 128 + m) * D + d];
    }
    #pragma unroll
    for (int it = 0; it < 4; ++it) s_local[tid + it * 256] = 0.f;

    float runZ[8];
    #pragma unroll
    for (int j = 0; j < 8; ++j) runZ[j] = 0.f;

    // ---- Pass 1: accumulate Z per column ----
    for (int nc = 0; nc < 8; ++nc) {
        __syncthreads();
        #pragma unroll
        for (int it = 0; it < 16; ++it) {
            int i = tid + it * 256;
            int n = i >> 5, d = i & 31;
            Kt[d][n] = Kb[(size_t)(nc * 128 + n) * D + d];
        }
        __syncthreads();

        float acc[8][8] = {};
        #pragma unroll 8
        for (int d = 0; d < 32; ++d) {
            float a[8], bb[8];
            *(float4*)&a[0]  = *(const float4*)&Kt[d][tn * 8];
            *(float4*)&a[4]  = *(const float4*)&Kt[d][tn * 8 + 4];
            *(float4*)&bb[0] = *(const float4*)&Qt[d][tm * 8];
            *(float4*)&bb[4] = *(const float4*)&Qt[d][tm * 8 + 4];
            #pragma unroll
            for (int i = 0; i < 8; ++i)
                #pragma unroll
                for (int j = 0; j < 8; ++j)
                    acc[i][j] += a[i] * bb[j];
        }
        #pragma unroll
        for (int j = 0; j < 8; ++j) {
            float z = 0.f;
            #pragma unroll
            for (int i = 0; i < 8; ++i) z += __expf(acc[i][j] * SCALE);
            runZ[j] += z;
        }
    }

    // ---- Reduce Z across the 16 row-groups ----
    #pragma unroll
    for (int j = 0; j < 8; ++j) redz[tn][tm * 8 + j] = runZ[j];
    __syncthreads();
    for (int st = 8; st >= 1; st >>= 1) {
        if (tn < st) {
            #pragma unroll
            for (int j = 0; j < 8; ++j)
                redz[tn][tm * 8 + j] += redz[tn + st][tm * 8 + j];
        }
        __syncthreads();
    }
    if (tid < 128) cinv[tid] = 1.0f / redz[0][tid];

    // ---- Pass 2: recompute S, accumulate row sums s[n] ----
    for (int nc = 0; nc < 8; ++nc) {
        __syncthreads();
        #pragma unroll
        for (int it = 0; it < 16; ++it) {
            int i = tid + it * 256;
            int n = i >> 5, d = i & 31;
            Kt[d][n] = Kb[(size_t)(nc * 128 + n) * D + d];
        }
        __syncthreads();

        float acc[8][8] = {};
        #pragma unroll 8
        for (int d = 0; d < 32; ++d) {
            float a[8], bb[8];
            *(float4*)&a[0]  = *(const float4*)&Kt[d][tn * 8];
            *(float4*)&a[4]  = *(const float4*)&Kt[d][tn * 8 + 4];
            *(float4*)&bb[0] = *(const float4*)&Qt[d][tm * 8];
            *(float4*)&bb[4] = *(const float4*)&Qt[d][tm * 8 + 4];
            #pragma unroll
            for (int i = 0; i < 8; ++i)
                #pragma unroll
                for (int j = 0; j < 8; ++j)
                    acc[i][j] += a[i] * bb[j];
        }
        float rp[8];
        #pragma unroll
        for (int i = 0; i < 8; ++i) rp[i] = 0.f;
        #pragma unroll
        for (int j = 0; j < 8; ++j) {
            float ci = cinv[tm * 8 + j];
            #pragma unroll
            for (int i = 0; i < 8; ++i)
                rp[i] += __expf(acc[i][j] * SCALE) * ci;
        }
        // staggered LDS atomics (2-way max contention)
        #pragma unroll
        for (int t = 0; t < 8; ++t) {
            int i = (t + tm) & 7;
            atomicAdd(&s_local[nc * 128 + tn * 8 + i], rp[i]);
        }
    }

    __syncthreads();
    float* sp = spart + (size_t)(bh * 8 + mc) * N;
    #pragma unroll
    for (int it = 0; it < 4; ++it) {
        int i = tid + it * 256;
        sp[i] = s_local[i];
    }
}

// ---------------- Kernel 3: reduce s partials over the 8 m-chunks --------------
__global__ __launch_bounds__(256) void reduce_s_kernel(
    const float* __restrict__ spart, float* __restrict__ sfull)
{
    int i = blockIdx.x * 256 + threadIdx.x;   // < BH*N = 65536
    int bh = i >> 10, n = i & (N - 1);
    float acc = 0.f;
    #pragma unroll
    for (int mc = 0; mc < 8; ++mc)
        acc += spart[(size_t)(bh * 8 + mc) * N + n];
    sfull[i] = acc;
}

// ---------------- Kernel 4: output GEMM (scaled V) ------------------------------
// out[r,c] = sum_k (Vh-scaled A)[r,k] * Wo[k,c] + bo[c]
__global__ __launch_bounds__(256) void out_kernel(
    const float* __restrict__ Vh, const float* __restrict__ sfull,
    const float* __restrict__ Wo, const float* __restrict__ bo,
    float* __restrict__ out)
{
    __shared__ float At[16][68];
    __shared__ float Bs[16][68];

    const int tid = threadIdx.x;
    const int tx = tid & 15, ty = tid >> 4;
    const int row0 = blockIdx.x * 64;
    const int col0 = blockIdx.y * 64;

    float acc[4][4] = {};

    for (int k0 = 0; k0 < E; k0 += 16) {
        __syncthreads();
        #pragma unroll
        for (int it = 0; it < 4; ++it) {
            int i = tid + it * 256;
            int k = i & 15, r = i >> 4;
            int gr = row0 + r;
            int b = gr >> 10, n = gr & (N - 1);
            int gc = k0 + k;
            int h = gc >> 5, dd = gc & 31;
            size_t rowIdx = (size_t)((b * H + h) * N + n);
            At[k][r] = Vh[rowIdx * D + dd] * sfull[rowIdx];
        }
        #pragma unroll
        for (int it = 0; it < 4; ++it) {
            int i = tid + it * 256;
            int c = i & 63, k = i >> 6;
            Bs[k][c] = Wo[(size_t)(k0 + k) * E + col0 + c];
        }
        __syncthreads();
        #pragma unroll
        for (int kk = 0; kk < 16; ++kk) {
            float a[4], b[4];
            #pragma unroll
            for (int i = 0; i < 4; ++i) a[i] = At[kk][ty * 4 + i];
            #pragma unroll
            for (int j = 0; j < 4; ++j) b[j] = Bs[kk][tx * 4 + j];
            #pragma unroll
            for (int i = 0; i < 4; ++i)
                #pragma unroll
                for (int j = 0; j < 4; ++j)
                    acc[i][j] += a[i] * b[j];
        }
    }

    #pragma unroll
    for (int i = 0; i < 4; ++i) {
        int gr = row0 + ty * 4 + i;
        #pragma unroll
        for (int j = 0; j < 4; ++j) {
            int gc = col0 + tx * 4 + j;
            out[(size_t)gr * E + gc] = acc[i][j] + bo[gc];
        }
    }
}

// --------------------------------------------------------------------------------
extern "C" void kernel_launch(void* const* d_in, const int* in_sizes, int n_in,
                              void* d_out, int out_size, void* d_ws, size_t ws_size,
                              hipStream_t stream) {
    const float* q_in = (const float*)d_in[0];
    const float* k_in = (const float*)d_in[1];
    const float* v_in = (const float*)d_in[2];
    const float* Wq = (const float*)d_in[3];
    const float* bq = (const float*)d_in[4];
    const float* Wk = (const float*)d_in[5];
    const float* bk = (const float*)d_in[6];
    const float* Wv = (const float*)d_in[7];
    const float* bv = (const float*)d_in[8];
    const float* Wo = (const float*)d_in[9];
    const float* bo = (const float*)d_in[10];
    float* out = (float*)d_out;

    float* ws    = (float*)d_ws;
    float* Qh    = ws;                 // 64*1024*32 = 2097152
    float* Kh    = ws + 2097152;
    float* Vh    = ws + 4194304;
    float* spart = ws + 6291456;       // 8*64*1024 = 524288
    float* sfull = ws + 6815744;       // 65536
    // total 6881280 floats = 27.5 MB of workspace

    dim3 pg(R / 64, E / 64, 3);
    proj_kernel<<<pg, 256, 0, stream>>>(q_in, k_in, v_in, Wq, bq, Wk, bk, Wv, bv, Qh, Kh, Vh);

    dim3 sg(BH, 8);
    scores_kernel<<<sg, 256, 0, stream>>>(Qh, Kh, spart);

    reduce_s_kernel<<<BH * N / 256, 256, 0, stream>>>(spart, sfull);

    dim3 og(R / 64, E / 64);
    out_kernel<<<og, 256, 0, stream>>>(Vh, sfull, Wo, bo, out);
}

// Round 2
// 132.113 us; speedup vs baseline: 1.7716x; 1.7716x over previous
//
#include <hip/hip_runtime.h>
#include <hip/hip_bf16.h>
#include <cstdint>
#include <cstddef>

// Problem constants (B=8, T=64, F=16, E=256, H=8)
constexpr int E = 256;
constexpr int H = 8;
constexpr int D = 32;        // head dim
constexpr int N = 1024;      // T*F positions per (b,h)
constexpr int R = 8192;      // B*N rows
constexpr int BH = 64;       // B*H
constexpr float SCALE = 0.17677669529663687f;   // 1/sqrt(32)
constexpr float LOG2E = 1.4426950408889634f;
constexpr float QSCALE = SCALE * LOG2E;          // folded into bf16 Q

typedef __attribute__((ext_vector_type(8))) short short8;
typedef __attribute__((ext_vector_type(4))) float f32x4;

// ---------------- Kernel 1: QKV projections, head-split scatter ----------------
// Q path: write bf16( (X@Wq+bq) * QSCALE )   -> Qb16[(b*H+h)*N+n][dd]
// K path: write bf16(  X@Wk+bk )             -> Kb16[...]
// V path: write fp32(  X@Wv+bv )             -> Vh[...]
__global__ __launch_bounds__(256) void proj_kernel(
    const float* __restrict__ q_in, const float* __restrict__ k_in, const float* __restrict__ v_in,
    const float* __restrict__ Wq, const float* __restrict__ bq,
    const float* __restrict__ Wk, const float* __restrict__ bk,
    const float* __restrict__ Wv, const float* __restrict__ bv,
    __hip_bfloat16* __restrict__ Qb16, __hip_bfloat16* __restrict__ Kb16,
    float* __restrict__ Vh)
{
    const int which = blockIdx.z;
    const float* X    = (which == 0) ? q_in : (which == 1) ? k_in : v_in;
    const float* W    = (which == 0) ? Wq   : (which == 1) ? Wk   : Wv;
    const float* bias = (which == 0) ? bq   : (which == 1) ? bk   : bv;

    __shared__ float At[16][68];   // A tile transposed: At[k][r]
    __shared__ float Bs[16][68];   // B tile: Bs[k][c]

    const int tid = threadIdx.x;
    const int tx = tid & 15, ty = tid >> 4;
    const int row0 = blockIdx.x * 64;
    const int col0 = blockIdx.y * 64;

    float acc[4][4] = {};

    for (int k0 = 0; k0 < E; k0 += 16) {
        __syncthreads();
        #pragma unroll
        for (int it = 0; it < 4; ++it) {
            int i = tid + it * 256;
            int k = i & 15, r = i >> 4;
            At[k][r] = X[(size_t)(row0 + r) * E + k0 + k];
        }
        #pragma unroll
        for (int it = 0; it < 4; ++it) {
            int i = tid + it * 256;
            int c = i & 63, k = i >> 6;
            Bs[k][c] = W[(size_t)(k0 + k) * E + col0 + c];
        }
        __syncthreads();
        #pragma unroll
        for (int kk = 0; kk < 16; ++kk) {
            float a[4], b[4];
            #pragma unroll
            for (int i = 0; i < 4; ++i) a[i] = At[kk][ty * 4 + i];
            #pragma unroll
            for (int j = 0; j < 4; ++j) b[j] = Bs[kk][tx * 4 + j];
            #pragma unroll
            for (int i = 0; i < 4; ++i)
                #pragma unroll
                for (int j = 0; j < 4; ++j)
                    acc[i][j] += a[i] * b[j];
        }
    }

    #pragma unroll
    for (int i = 0; i < 4; ++i) {
        int gr = row0 + ty * 4 + i;
        int b = gr >> 10, n = gr & (N - 1);
        #pragma unroll
        for (int j = 0; j < 4; ++j) {
            int gc = col0 + tx * 4 + j;
            int h = gc >> 5, dd = gc & 31;
            size_t idx = ((size_t)((b * H + h) * N + n)) * D + dd;
            float v = acc[i][j] + bias[gc];
            if (which == 0)      Qb16[idx] = __float2bfloat16(v * QSCALE);
            else if (which == 1) Kb16[idx] = __float2bfloat16(v);
            else                 Vh[idx]   = v;
        }
    }
}

// ---------------- Kernel 2: MFMA scores + softmax-denominator + s partials -----
// Per block: one (b,h), 128 query columns (mc). 4 waves; wave owns 2 m-tiles.
// S_exp[n,m] = exp2( sum_d Kb16[n,d] * Qb16[m,d] )   (scale pre-folded into Q)
// Pass 1: Z_m = sum_n S_exp[n,m]  (no max subtraction: |S| small, fp32-safe)
// Pass 2: s_part[n] = sum_{m in chunk} S_exp[n,m] / Z_m
__global__ __launch_bounds__(256) void scores_kernel(
    const __hip_bfloat16* __restrict__ Qb16, const __hip_bfloat16* __restrict__ Kb16,
    float* __restrict__ spart)
{
    const int bh = blockIdx.x;   // 0..63
    const int mc = blockIdx.y;   // 0..7  (columns mc*128 .. +128)
    const int tid  = threadIdx.x;
    const int wave = tid >> 6;   // 0..3
    const int lane = tid & 63;
    const int l15  = lane & 15;
    const int lhi  = lane >> 4;  // 0..3

    const short* Qb = (const short*)Qb16 + (size_t)bh * (N * D);
    const short* Kb = (const short*)Kb16 + (size_t)bh * (N * D);

    __shared__ float swave[4][1024];   // per-wave row-sum partials (16 KB)

    // Load this wave's 2 Q fragments (held in registers for both passes).
    // B-frag layout: col = lane&15, k = (lane>>4)*8 + j  -> 16B row slice.
    short8 qf[2];
    #pragma unroll
    for (int t = 0; t < 2; ++t) {
        int m = mc * 128 + (wave * 2 + t) * 16 + l15;
        qf[t] = *(const short8*)(Qb + (size_t)m * D + lhi * 8);
    }

    // ---- Pass 1: Z per column ----
    float z[2] = {0.f, 0.f};
    #pragma unroll 4
    for (int nt = 0; nt < 64; ++nt) {
        short8 kf = *(const short8*)(Kb + (size_t)(nt * 16 + l15) * D + lhi * 8);
        #pragma unroll
        for (int t = 0; t < 2; ++t) {
            f32x4 acc = {0.f, 0.f, 0.f, 0.f};
            acc = __builtin_amdgcn_mfma_f32_16x16x32_bf16(kf, qf[t], acc, 0, 0, 0);
            z[t] += exp2f(acc[0]) + exp2f(acc[1]) + exp2f(acc[2]) + exp2f(acc[3]);
        }
    }
    // Reduce across the 4 row-groups (lanes l, l^16, l^32, l^48 share a column)
    #pragma unroll
    for (int t = 0; t < 2; ++t) {
        z[t] += __shfl_xor(z[t], 16);
        z[t] += __shfl_xor(z[t], 32);
    }
    float cinv[2] = {1.0f / z[0], 1.0f / z[1]};

    // ---- Pass 2: recompute, accumulate row sums ----
    #pragma unroll 2
    for (int nt = 0; nt < 64; ++nt) {
        short8 kf = *(const short8*)(Kb + (size_t)(nt * 16 + l15) * D + lhi * 8);
        float rp[4] = {0.f, 0.f, 0.f, 0.f};
        #pragma unroll
        for (int t = 0; t < 2; ++t) {
            f32x4 acc = {0.f, 0.f, 0.f, 0.f};
            acc = __builtin_amdgcn_mfma_f32_16x16x32_bf16(kf, qf[t], acc, 0, 0, 0);
            #pragma unroll
            for (int j = 0; j < 4; ++j)
                rp[j] += exp2f(acc[j]) * cinv[t];
        }
        // Sum over the 16 columns held by this 16-lane group (rows stay per-lane)
        #pragma unroll
        for (int mask = 1; mask <= 8; mask <<= 1)
            #pragma unroll
            for (int j = 0; j < 4; ++j)
                rp[j] += __shfl_xor(rp[j], mask);
        if (l15 == 0) {
            #pragma unroll
            for (int j = 0; j < 4; ++j)
                swave[wave][nt * 16 + lhi * 4 + j] = rp[j];
        }
    }
    __syncthreads();

    float* sp = spart + (size_t)(bh * 8 + mc) * N;
    #pragma unroll
    for (int it = 0; it < 4; ++it) {
        int i = tid + it * 256;
        sp[i] = swave[0][i] + swave[1][i] + swave[2][i] + swave[3][i];
    }
}

// ---------------- Kernel 3: reduce s partials over the 8 m-chunks --------------
__global__ __launch_bounds__(256) void reduce_s_kernel(
    const float* __restrict__ spart, float* __restrict__ sfull)
{
    int i = blockIdx.x * 256 + threadIdx.x;   // < BH*N = 65536
    int bh = i >> 10, n = i & (N - 1);
    float acc = 0.f;
    #pragma unroll
    for (int mc = 0; mc < 8; ++mc)
        acc += spart[(size_t)(bh * 8 + mc) * N + n];
    sfull[i] = acc;
}

// ---------------- Kernel 4: output GEMM (scaled V) ------------------------------
__global__ __launch_bounds__(256) void out_kernel(
    const float* __restrict__ Vh, const float* __restrict__ sfull,
    const float* __restrict__ Wo, const float* __restrict__ bo,
    float* __restrict__ out)
{
    __shared__ float At[16][68];
    __shared__ float Bs[16][68];

    const int tid = threadIdx.x;
    const int tx = tid & 15, ty = tid >> 4;
    const int row0 = blockIdx.x * 64;
    const int col0 = blockIdx.y * 64;

    float acc[4][4] = {};

    for (int k0 = 0; k0 < E; k0 += 16) {
        __syncthreads();
        #pragma unroll
        for (int it = 0; it < 4; ++it) {
            int i = tid + it * 256;
            int k = i & 15, r = i >> 4;
            int gr = row0 + r;
            int b = gr >> 10, n = gr & (N - 1);
            int gc = k0 + k;
            int h = gc >> 5, dd = gc & 31;
            size_t rowIdx = (size_t)((b * H + h) * N + n);
            At[k][r] = Vh[rowIdx * D + dd] * sfull[rowIdx];
        }
        #pragma unroll
        for (int it = 0; it < 4; ++it) {
            int i = tid + it * 256;
            int c = i & 63, k = i >> 6;
            Bs[k][c] = Wo[(size_t)(k0 + k) * E + col0 + c];
        }
        __syncthreads();
        #pragma unroll
        for (int kk = 0; kk < 16; ++kk) {
            float a[4], b[4];
            #pragma unroll
            for (int i = 0; i < 4; ++i) a[i] = At[kk][ty * 4 + i];
            #pragma unroll
            for (int j = 0; j < 4; ++j) b[j] = Bs[kk][tx * 4 + j];
            #pragma unroll
            for (int i = 0; i < 4; ++i)
                #pragma unroll
                for (int j = 0; j < 4; ++j)
                    acc[i][j] += a[i] * b[j];
        }
    }

    #pragma unroll
    for (int i = 0; i < 4; ++i) {
        int gr = row0 + ty * 4 + i;
        #pragma unroll
        for (int j = 0; j < 4; ++j) {
            int gc = col0 + tx * 4 + j;
            out[(size_t)gr * E + gc] = acc[i][j] + bo[gc];
        }
    }
}

// --------------------------------------------------------------------------------
extern "C" void kernel_launch(void* const* d_in, const int* in_sizes, int n_in,
                              void* d_out, int out_size, void* d_ws, size_t ws_size,
                              hipStream_t stream) {
    const float* q_in = (const float*)d_in[0];
    const float* k_in = (const float*)d_in[1];
    const float* v_in = (const float*)d_in[2];
    const float* Wq = (const float*)d_in[3];
    const float* bq = (const float*)d_in[4];
    const float* Wk = (const float*)d_in[5];
    const float* bk = (const float*)d_in[6];
    const float* Wv = (const float*)d_in[7];
    const float* bv = (const float*)d_in[8];
    const float* Wo = (const float*)d_in[9];
    const float* bo = (const float*)d_in[10];
    float* out = (float*)d_out;

    // Workspace layout (byte offsets):
    //   Vh    fp32  [BH*N*D]  @ 0        (8 MB)
    //   Qb16  bf16  [BH*N*D]  @ 8 MB     (4 MB)
    //   Kb16  bf16  [BH*N*D]  @ 12 MB    (4 MB)
    //   spart fp32  [BH*8*N]  @ 16 MB    (2 MB)
    //   sfull fp32  [BH*N]    @ 18 MB    (256 KB)
    char* ws = (char*)d_ws;
    float*          Vh    = (float*)ws;
    __hip_bfloat16* Qb16  = (__hip_bfloat16*)(ws + (8u << 20));
    __hip_bfloat16* Kb16  = (__hip_bfloat16*)(ws + (12u << 20));
    float*          spart = (float*)(ws + (16u << 20));
    float*          sfull = (float*)(ws + (18u << 20));

    dim3 pg(R / 64, E / 64, 3);
    proj_kernel<<<pg, 256, 0, stream>>>(q_in, k_in, v_in, Wq, bq, Wk, bk, Wv, bv,
                                        Qb16, Kb16, Vh);

    dim3 sg(BH, 8);
    scores_kernel<<<sg, 256, 0, stream>>>(Qb16, Kb16, spart);

    reduce_s_kernel<<<BH * N / 256, 256, 0, stream>>>(spart, sfull);

    dim3 og(R / 64, E / 64);
    out_kernel<<<og, 256, 0, stream>>>(Vh, sfull, Wo, bo, out);
}

// Round 3
// 97.133 us; speedup vs baseline: 2.4096x; 1.3601x over previous
//
#include <hip/hip_runtime.h>
#include <hip/hip_bf16.h>
#include <cstdint>
#include <cstddef>

// Problem constants (B=8, T=64, F=16, E=256, H=8)
constexpr int E = 256;
constexpr int H = 8;
constexpr int D = 32;        // head dim
constexpr int N = 1024;      // T*F positions per (b,h)
constexpr int R = 8192;      // B*N rows
constexpr int BH = 64;       // B*H
constexpr float SCALE = 0.17677669529663687f;   // 1/sqrt(32)
constexpr float LOG2E = 1.4426950408889634f;
constexpr float QSCALE = SCALE * LOG2E;          // folded into bf16 Q

typedef __attribute__((ext_vector_type(8))) short short8;
typedef __attribute__((ext_vector_type(4))) float f32x4;

static __device__ __forceinline__ short bf16bits(float x) {
    __hip_bfloat16 h = __float2bfloat16(x);
    return *reinterpret_cast<short*>(&h);
}

// ---------------- Kernel A: convert inputs fp32 -> bf16 (row-major) ------------
__global__ __launch_bounds__(256) void convx_kernel(
    const float* __restrict__ q_in, const float* __restrict__ k_in,
    const float* __restrict__ v_in, short* __restrict__ Xb16)
{
    const int which = blockIdx.y;
    const float* src = (which == 0) ? q_in : (which == 1) ? k_in : v_in;
    short* dst = Xb16 + (size_t)which * R * E;
    int i0 = (blockIdx.x * 256 + threadIdx.x) * 8;   // 1024 blocks cover 2M elems
    float4 a = *(const float4*)(src + i0);
    float4 b = *(const float4*)(src + i0 + 4);
    short tmp[8];
    tmp[0] = bf16bits(a.x); tmp[1] = bf16bits(a.y); tmp[2] = bf16bits(a.z); tmp[3] = bf16bits(a.w);
    tmp[4] = bf16bits(b.x); tmp[5] = bf16bits(b.y); tmp[6] = bf16bits(b.z); tmp[7] = bf16bits(b.w);
    *(short8*)(dst + i0) = *(short8*)tmp;
}

// ---------------- Kernel B: transpose weights fp32 -> bf16 ---------------------
// Wt4[w][n][k] = W_w[k][n],  w in {q,k,v,o}
__global__ __launch_bounds__(256) void convw_kernel(
    const float* __restrict__ Wq, const float* __restrict__ Wk,
    const float* __restrict__ Wv, const float* __restrict__ Wo,
    short* __restrict__ Wt4)
{
    const int w = blockIdx.y;
    const float* src = (w == 0) ? Wq : (w == 1) ? Wk : (w == 2) ? Wv : Wo;
    short* dst = Wt4 + (size_t)w * E * E;
    const int tr = blockIdx.x >> 2, tc = blockIdx.x & 3;   // 64x64 tiles
    __shared__ float tile[64][65];
    const int tid = threadIdx.x;
    #pragma unroll
    for (int it = 0; it < 16; ++it) {
        int idx = tid + it * 256;
        int r = idx >> 6, c = idx & 63;
        tile[r][c] = src[(size_t)(tr * 64 + r) * E + tc * 64 + c];
    }
    __syncthreads();
    #pragma unroll
    for (int it = 0; it < 16; ++it) {
        int idx = tid + it * 256;
        int r = idx >> 6, c = idx & 63;
        dst[(size_t)(tc * 64 + r) * E + tr * 64 + c] = bf16bits(tile[c][r]);
    }
}

// ---------------- Kernel C: QKV projections via MFMA ---------------------------
// P = Xb16 @ W + bias. Q -> bf16 head-split *QSCALE; K -> bf16 head-split; V -> fp32 row-major.
__global__ __launch_bounds__(256) void proj_mfma(
    const short* __restrict__ Xb16, const short* __restrict__ Wt4,
    const float* __restrict__ bq, const float* __restrict__ bk, const float* __restrict__ bv,
    __hip_bfloat16* __restrict__ Qb16, __hip_bfloat16* __restrict__ Kb16,
    float* __restrict__ Vh)
{
    const int which = blockIdx.z;
    const short* X  = Xb16 + (size_t)which * R * E;
    const short* Wt = Wt4 + (size_t)which * E * E;
    const float* bias = (which == 0) ? bq : (which == 1) ? bk : bv;

    const int wave = threadIdx.x >> 6, lane = threadIdx.x & 63;
    const int l15 = lane & 15, lhi = lane >> 4;
    const int m0 = blockIdx.x * 64 + wave * 16;
    const int n0 = blockIdx.y * 64;

    f32x4 acc[4] = {};
    for (int k0 = 0; k0 < E; k0 += 32) {
        short8 af = *(const short8*)(X + (size_t)(m0 + l15) * E + k0 + lhi * 8);
        #pragma unroll
        for (int nt = 0; nt < 4; ++nt) {
            short8 bf = *(const short8*)(Wt + (size_t)(n0 + nt * 16 + l15) * E + k0 + lhi * 8);
            acc[nt] = __builtin_amdgcn_mfma_f32_16x16x32_bf16(af, bf, acc[nt], 0, 0, 0);
        }
    }
    // D layout: row m = m0 + lhi*4 + j (A rows), col n = n0 + nt*16 + l15 (B rows)
    #pragma unroll
    for (int nt = 0; nt < 4; ++nt) {
        #pragma unroll
        for (int j = 0; j < 4; ++j) {
            int m = m0 + lhi * 4 + j;
            int n = n0 + nt * 16 + l15;
            float v = acc[nt][j] + bias[n];
            if (which == 2) {
                Vh[(size_t)m * E + n] = v;
            } else {
                int b = m >> 10, nl = m & (N - 1);
                int h = n >> 5, dd = n & 31;
                size_t idx = ((size_t)((b * H + h) * N + nl)) * D + dd;
                if (which == 0) Qb16[idx] = __float2bfloat16(v * QSCALE);
                else            Kb16[idx] = __float2bfloat16(v);
            }
        }
    }
}

// ---------------- Kernel D: scores (swapped-operand MFMA softmax) --------------
// Per block: one (b,h), 128 query columns (mc). 8 waves; wave owns 8 n-tiles,
// all 8 m-tiles. acc = mfma(qf, kf): lane holds rows m (lane-local!), col n=l15.
// Pass 1: Z_m = sum_n exp2(acc)  -> butterfly over l15 ONCE at end.
// Pass 2: s_n = sum_m exp2(acc)*cinv_m -> in-lane sum + 2 shuffles per n-tile.
__global__ __launch_bounds__(512, 4) void scores_kernel(
    const __hip_bfloat16* __restrict__ Qb16, const __hip_bfloat16* __restrict__ Kb16,
    float* __restrict__ spart)
{
    const int bh = blockIdx.x;   // 0..63
    const int mc = blockIdx.y;   // 0..7
    const int tid  = threadIdx.x;
    const int wave = tid >> 6;   // 0..7
    const int lane = tid & 63;
    const int l15  = lane & 15;
    const int lhi  = lane >> 4;  // 0..3

    const short* Qb = (const short*)Qb16 + (size_t)bh * (N * D);
    const short* Kb = (const short*)Kb16 + (size_t)bh * (N * D);

    __shared__ float zred[8][128];
    __shared__ float cinvS[128];

    // Wave's 8 Q fragments (A operand): rows m = mc*128 + t*16 + l15
    short8 qf[8];
    #pragma unroll
    for (int t = 0; t < 8; ++t) {
        int m = mc * 128 + t * 16 + l15;
        qf[t] = *(const short8*)(Qb + (size_t)m * D + lhi * 8);
    }

    // ---- Pass 1: Z partials over this wave's 128 n rows ----
    float z[8][4];
    #pragma unroll
    for (int t = 0; t < 8; ++t)
        #pragma unroll
        for (int j = 0; j < 4; ++j) z[t][j] = 0.f;

    #pragma unroll 2
    for (int ntl = 0; ntl < 8; ++ntl) {
        int nt = wave * 8 + ntl;
        short8 kf = *(const short8*)(Kb + (size_t)(nt * 16 + l15) * D + lhi * 8);
        #pragma unroll
        for (int t = 0; t < 8; ++t) {
            f32x4 acc = {0.f, 0.f, 0.f, 0.f};
            acc = __builtin_amdgcn_mfma_f32_16x16x32_bf16(qf[t], kf, acc, 0, 0, 0);
            #pragma unroll
            for (int j = 0; j < 4; ++j) z[t][j] += exp2f(acc[j]);
        }
    }
    // butterfly over l15 (sums the 16 n's per tile; nts already accumulated)
    #pragma unroll
    for (int t = 0; t < 8; ++t)
        #pragma unroll
        for (int j = 0; j < 4; ++j) {
            float v = z[t][j];
            v += __shfl_xor(v, 1); v += __shfl_xor(v, 2);
            v += __shfl_xor(v, 4); v += __shfl_xor(v, 8);
            z[t][j] = v;
        }
    // z[t][j] now = partial Z for column m_local = t*16 + lhi*4 + j (this wave's n range)
    #pragma unroll
    for (int t = 0; t < 8; ++t) {
        if (l15 == t) {
            #pragma unroll
            for (int j = 0; j < 4; ++j)
                zred[wave][t * 16 + lhi * 4 + j] = z[t][j];
        }
    }
    __syncthreads();
    if (tid < 128) {
        float zs = 0.f;
        #pragma unroll
        for (int w = 0; w < 8; ++w) zs += zred[w][tid];
        cinvS[tid] = 1.0f / zs;
    }
    __syncthreads();

    float ci[8][4];
    #pragma unroll
    for (int t = 0; t < 8; ++t)
        #pragma unroll
        for (int j = 0; j < 4; ++j) ci[t][j] = cinvS[t * 16 + lhi * 4 + j];

    // ---- Pass 2: recompute, in-lane weighted sum over m, write s partials ----
    float* sp = spart + (size_t)(bh * 8 + mc) * N;
    #pragma unroll 2
    for (int ntl = 0; ntl < 8; ++ntl) {
        int nt = wave * 8 + ntl;
        short8 kf = *(const short8*)(Kb + (size_t)(nt * 16 + l15) * D + lhi * 8);
        float rp = 0.f;
        #pragma unroll
        for (int t = 0; t < 8; ++t) {
            f32x4 acc = {0.f, 0.f, 0.f, 0.f};
            acc = __builtin_amdgcn_mfma_f32_16x16x32_bf16(qf[t], kf, acc, 0, 0, 0);
            #pragma unroll
            for (int j = 0; j < 4; ++j) rp += exp2f(acc[j]) * ci[t][j];
        }
        // sum over the 4 lhi groups (each holds 32 of the 128 m's); n = nt*16 + l15
        rp += __shfl_xor(rp, 16);
        rp += __shfl_xor(rp, 32);
        if (lane < 16) sp[nt * 16 + l15] = rp;
    }
}

// ---------------- Kernel E: reduce s over m-chunks + scale V -> bf16 -----------
// thread j: r = j>>3 (global row), h = j&7. s = sum_mc spart[bh][mc][n].
// Vb16s[r][h*32+dd] = bf16(Vh[r][h*32+dd] * s)
__global__ __launch_bounds__(256) void vscale_kernel(
    const float* __restrict__ spart, const float* __restrict__ Vh,
    short* __restrict__ Vb16s)
{
    int j = blockIdx.x * 256 + threadIdx.x;   // < 65536
    int r = j >> 3, h = j & 7;
    int b = r >> 10, nl = r & (N - 1);
    int bh = b * H + h;
    float s = 0.f;
    #pragma unroll
    for (int mc = 0; mc < 8; ++mc)
        s += spart[(size_t)(bh * 8 + mc) * N + nl];

    const float* vsrc = Vh + (size_t)r * E + h * 32;
    short* vdst = Vb16s + (size_t)r * E + h * 32;
    #pragma unroll
    for (int q = 0; q < 4; ++q) {
        float4 a = *(const float4*)(vsrc + q * 8);
        float4 c = *(const float4*)(vsrc + q * 8 + 4);
        short tmp[8];
        tmp[0] = bf16bits(a.x * s); tmp[1] = bf16bits(a.y * s);
        tmp[2] = bf16bits(a.z * s); tmp[3] = bf16bits(a.w * s);
        tmp[4] = bf16bits(c.x * s); tmp[5] = bf16bits(c.y * s);
        tmp[6] = bf16bits(c.z * s); tmp[7] = bf16bits(c.w * s);
        *(short8*)(vdst + q * 8) = *(short8*)tmp;
    }
}

// ---------------- Kernel F: output GEMM via MFMA -------------------------------
// out = Vb16s @ Wo + bo  (fp32 out)
__global__ __launch_bounds__(256) void out_mfma(
    const short* __restrict__ Vb16s, const short* __restrict__ Wt4,
    const float* __restrict__ bo, float* __restrict__ out)
{
    const short* Wot = Wt4 + (size_t)3 * E * E;
    const int wave = threadIdx.x >> 6, lane = threadIdx.x & 63;
    const int l15 = lane & 15, lhi = lane >> 4;
    const int m0 = blockIdx.x * 64 + wave * 16;
    const int n0 = blockIdx.y * 64;

    f32x4 acc[4] = {};
    for (int k0 = 0; k0 < E; k0 += 32) {
        short8 af = *(const short8*)(Vb16s + (size_t)(m0 + l15) * E + k0 + lhi * 8);
        #pragma unroll
        for (int nt = 0; nt < 4; ++nt) {
            short8 bf = *(const short8*)(Wot + (size_t)(n0 + nt * 16 + l15) * E + k0 + lhi * 8);
            acc[nt] = __builtin_amdgcn_mfma_f32_16x16x32_bf16(af, bf, acc[nt], 0, 0, 0);
        }
    }
    #pragma unroll
    for (int nt = 0; nt < 4; ++nt) {
        #pragma unroll
        for (int j = 0; j < 4; ++j) {
            int m = m0 + lhi * 4 + j;
            int n = n0 + nt * 16 + l15;
            out[(size_t)m * E + n] = acc[nt][j] + bo[n];
        }
    }
}

// --------------------------------------------------------------------------------
extern "C" void kernel_launch(void* const* d_in, const int* in_sizes, int n_in,
                              void* d_out, int out_size, void* d_ws, size_t ws_size,
                              hipStream_t stream) {
    const float* q_in = (const float*)d_in[0];
    const float* k_in = (const float*)d_in[1];
    const float* v_in = (const float*)d_in[2];
    const float* Wq = (const float*)d_in[3];
    const float* bq = (const float*)d_in[4];
    const float* Wk = (const float*)d_in[5];
    const float* bk = (const float*)d_in[6];
    const float* Wv = (const float*)d_in[7];
    const float* bv = (const float*)d_in[8];
    const float* Wo = (const float*)d_in[9];
    const float* bo = (const float*)d_in[10];
    float* out = (float*)d_out;

    // Workspace layout (bytes). Xb16 (12 MB) is dead after proj_mfma, so spart
    // and Vb16s alias into it (written only by later kernels, every call).
    //   Xb16  bf16 [3][R][E]   @ 0          (12 MB)
    //     spart fp32 [BH*8][N]   @ 0          (2 MB,  aliases dead Xq)
    //     Vb16s bf16 [R][E]      @ 4 MB       (4 MB,  aliases dead Xk)
    //   Wt4   bf16 [4][E][E]   @ 12 MB      (512 KB)
    //   Qb16  bf16 [BH][N][D]  @ 12.5 MB    (4 MB)
    //   Kb16  bf16 [BH][N][D]  @ 16.5 MB    (4 MB)
    //   Vh    fp32 [R][E]      @ 20.5 MB    (8 MB)   -> total 28.5 MB
    char* ws = (char*)d_ws;
    short*          Xb16  = (short*)ws;
    float*          spart = (float*)ws;
    short*          Vb16s = (short*)(ws + (4u << 20));
    short*          Wt4   = (short*)(ws + (12u << 20));
    __hip_bfloat16* Qb16  = (__hip_bfloat16*)(ws + (12u << 20) + (512u << 10));
    __hip_bfloat16* Kb16  = (__hip_bfloat16*)(ws + (16u << 20) + (512u << 10));
    float*          Vh    = (float*)(ws + (20u << 20) + (512u << 10));

    convx_kernel<<<dim3(1024, 3), 256, 0, stream>>>(q_in, k_in, v_in, Xb16);
    convw_kernel<<<dim3(16, 4), 256, 0, stream>>>(Wq, Wk, Wv, Wo, Wt4);

    proj_mfma<<<dim3(R / 64, E / 64, 3), 256, 0, stream>>>(
        Xb16, Wt4, bq, bk, bv, Qb16, Kb16, Vh);

    scores_kernel<<<dim3(BH, 8), 512, 0, stream>>>(Qb16, Kb16, spart);

    vscale_kernel<<<BH * N / 256, 256, 0, stream>>>(spart, Vh, Vb16s);

    out_mfma<<<dim3(R / 64, E / 64), 256, 0, stream>>>(Vb16s, Wt4, bo, out);
}